// Round 8
// baseline (131.956 us; speedup 1.0000x reference)
//
#include <hip/hip_runtime.h>
#include <hip/hip_bf16.h>

#define LSEQ   1024
#define NHEAD  8
#define DH     64
#define DIM    512
#define CHUNK  64
#define NCHUNK 16
#define NHTOT  16
#define LDB    68    // ushort LDS row stride for proj
#define LDA    72    // ushort LDS row stride for attn/chunksum (144 B, 16B-aligned)

typedef __attribute__((ext_vector_type(8))) short short8;
typedef __attribute__((ext_vector_type(4))) float floatx4;

__device__ __forceinline__ float softplusf_(float x) {
    if (x > 20.f) return x;
    return log1pf(expf(x));
}
__device__ __forceinline__ unsigned short bf16_rne(float x) {
    unsigned int u = __float_as_uint(x);
    u += 0x7FFFu + ((u >> 16) & 1u);
    return (unsigned short)(u >> 16);
}
__device__ __forceinline__ float bf16_tof(unsigned short h) {
    return __uint_as_float(((unsigned int)h) << 16);
}

// ---------------------------------------------------------------------------
// Kernel A: C = X @ W^T, single-pass bf16 MFMA.  64x64 tile, grid (32,8,3).
// Output: bf16 [n*H+h][l][d] (downstream consumers quantize to bf16 anyway).
// ---------------------------------------------------------------------------
__global__ __launch_bounds__(256) void proj_kernel(
    const float* __restrict__ query, const float* __restrict__ key,
    const float* __restrict__ Wq, const float* __restrict__ Wk,
    const float* __restrict__ Wv,
    unsigned short* __restrict__ qbuf, unsigned short* __restrict__ kbuf,
    unsigned short* __restrict__ vbuf)
{
    const int mt  = blockIdx.x;
    const int ot  = blockIdx.y;
    const int sel = blockIdx.z;
    const int t   = threadIdx.x;

    const float* __restrict__ X = (sel == 0) ? query : key;
    const float* __restrict__ W = (sel == 0) ? Wq : (sel == 1) ? Wk : Wv;
    unsigned short* __restrict__ obuf = (sel == 0) ? qbuf : (sel == 1) ? kbuf : vbuf;

    __shared__ unsigned short As[64 * LDB];
    __shared__ unsigned short Bs[64 * LDB];

    const int m0 = mt * 64, o0 = ot * 64;
    const int lane = t & 63, wave = t >> 6;
    const int quad = lane >> 4, l16 = lane & 15;
    const int wm = wave >> 1, wn = wave & 1;

    const int srow = t >> 2;
    const int sc16 = (t & 3) * 16;

    floatx4 acc[2][2];
    #pragma unroll
    for (int i = 0; i < 2; ++i)
        #pragma unroll
        for (int j = 0; j < 2; ++j) acc[i][j] = (floatx4){0.f, 0.f, 0.f, 0.f};

    float4 ax[4], bx4[4];
    #pragma unroll
    for (int i = 0; i < 4; ++i) {
        ax[i]  = *(const float4*)&X[(size_t)(m0 + srow) * DIM + sc16 + i * 4];
        bx4[i] = *(const float4*)&W[(size_t)(o0 + srow) * DIM + sc16 + i * 4];
    }

    for (int kt = 0; kt < DIM; kt += 64) {
        __syncthreads();
        {
            short8 a0, a1, b0, b1;
            #pragma unroll
            for (int i = 0; i < 2; ++i) {
                const float va[4] = {ax[i].x, ax[i].y, ax[i].z, ax[i].w};
                const float vb[4] = {bx4[i].x, bx4[i].y, bx4[i].z, bx4[i].w};
                #pragma unroll
                for (int j = 0; j < 4; ++j) {
                    a0[i * 4 + j] = (short)bf16_rne(va[j]);
                    b0[i * 4 + j] = (short)bf16_rne(vb[j]);
                }
            }
            #pragma unroll
            for (int i = 2; i < 4; ++i) {
                const float va[4] = {ax[i].x, ax[i].y, ax[i].z, ax[i].w};
                const float vb[4] = {bx4[i].x, bx4[i].y, bx4[i].z, bx4[i].w};
                #pragma unroll
                for (int j = 0; j < 4; ++j) {
                    a1[(i - 2) * 4 + j] = (short)bf16_rne(va[j]);
                    b1[(i - 2) * 4 + j] = (short)bf16_rne(vb[j]);
                }
            }
            *(short8*)&As[srow * LDB + sc16]     = a0;
            *(short8*)&As[srow * LDB + sc16 + 8] = a1;
            *(short8*)&Bs[srow * LDB + sc16]     = b0;
            *(short8*)&Bs[srow * LDB + sc16 + 8] = b1;
        }
        __syncthreads();

        if (kt + 64 < DIM) {
            #pragma unroll
            for (int i = 0; i < 4; ++i) {
                ax[i]  = *(const float4*)&X[(size_t)(m0 + srow) * DIM + kt + 64 + sc16 + i * 4];
                bx4[i] = *(const float4*)&W[(size_t)(o0 + srow) * DIM + kt + 64 + sc16 + i * 4];
            }
        }

        #pragma unroll
        for (int s = 0; s < 2; ++s) {
            short8 af[2], bf[2];
            #pragma unroll
            for (int mi = 0; mi < 2; ++mi)
                af[mi] = *(const short8*)&As[(wm * 32 + mi * 16 + l16) * LDB + s * 32 + quad * 8];
            #pragma unroll
            for (int ni = 0; ni < 2; ++ni)
                bf[ni] = *(const short8*)&Bs[(wn * 32 + ni * 16 + l16) * LDB + s * 32 + quad * 8];
            #pragma unroll
            for (int ni = 0; ni < 2; ++ni)
                #pragma unroll
                for (int mi = 0; mi < 2; ++mi)
                    acc[mi][ni] = __builtin_amdgcn_mfma_f32_16x16x32_bf16(af[mi], bf[ni], acc[mi][ni], 0, 0, 0);
        }
    }

    const int h = ot;
    #pragma unroll
    for (int mi = 0; mi < 2; ++mi)
        #pragma unroll
        for (int ni = 0; ni < 2; ++ni) {
            const int d = wn * 32 + ni * 16 + l16;
            #pragma unroll
            for (int r = 0; r < 4; ++r) {
                const int m = m0 + wm * 32 + mi * 16 + quad * 4 + r;
                const int n = m >> 10, l = m & (LSEQ - 1);
                float val = acc[mi][ni][r];
                if (sel < 2) val = softplusf_(val);
                obuf[(((size_t)(n * NHEAD + h)) * LSEQ + l) * DH + d] = bf16_rne(val);
            }
        }
}

// ---------------------------------------------------------------------------
// Kernel B (MFMA): per-(c,nh,br) chunk sums, stored TRANSPOSED f32:
//   Ssum[br][nh][c][e][d] = sum_k v[k][e]*kf[k][d];  zsum[...][d] = sum_k kf[k][d]
// One 64x64x64 bf16 GEMM per block (A=v^T [e][k], B=kf^T [d][k]).
// ---------------------------------------------------------------------------
__global__ __launch_bounds__(256) void chunksum_kernel(
    const unsigned short* __restrict__ kbuf, const unsigned short* __restrict__ vbuf,
    const float* __restrict__ pw,
    float* __restrict__ Ssum, float* __restrict__ zsum)
{
    const int c  = blockIdx.x;
    const int nh = blockIdx.y;
    const int br = blockIdx.z;
    const int h  = nh & (NHEAD - 1);
    const int t  = threadIdx.x;
    const int lane = t & 63, wave = t >> 6;
    const int quad = lane >> 4, l16 = lane & 15;
    const int wm = wave >> 1, wn = wave & 1;

    __shared__ unsigned short kfT[64 * LDA];  // [d][k]
    __shared__ unsigned short vT[64 * LDA];   // [e][k]
    __shared__ float dpart[4][64];

    const size_t base = ((size_t)nh * LSEQ + (size_t)c * CHUNK) * DH;

    #pragma unroll
    for (int i = 0; i < 4; ++i) {
        const int idx = i * 256 + t;
        const int r  = idx >> 4;          // k
        const int c4 = (idx & 15) * 4;    // d / e base
        const ushort4 kv = *(const ushort4*)&kbuf[base + (size_t)r * DH + c4];
        const ushort4 vv = *(const ushort4*)&vbuf[base + (size_t)r * DH + c4];
        const unsigned short* pk = (const unsigned short*)&kv;
        const unsigned short* pv = (const unsigned short*)&vv;
        float tk[4] = {1.f, 1.f, 1.f, 1.f};
        if (br != 0) {
            const float4 wv = *(const float4*)&pw[h * DH + c4];
            const float w4[4] = {wv.x, wv.y, wv.z, wv.w};
            const float pos = (float)(c * CHUNK + r);
            #pragma unroll
            for (int j = 0; j < 4; ++j)
                tk[j] = (br == 1) ? cosf(pos * w4[j]) : sinf(pos * w4[j]);
        }
        #pragma unroll
        for (int j = 0; j < 4; ++j) {
            kfT[(c4 + j) * LDA + r] = (br == 0) ? pk[j]
                                     : bf16_rne(bf16_tof(pk[j]) * tk[j]);
            vT[(c4 + j) * LDA + r] = pv[j];
        }
    }
    __syncthreads();

    floatx4 acc[2][2];
    #pragma unroll
    for (int i = 0; i < 2; ++i)
        #pragma unroll
        for (int j = 0; j < 2; ++j) acc[i][j] = (floatx4){0.f, 0.f, 0.f, 0.f};

    #pragma unroll
    for (int kk = 0; kk < 2; ++kk) {
        short8 a[2], b[2];
        #pragma unroll
        for (int mi = 0; mi < 2; ++mi)
            a[mi] = *(const short8*)&vT[(wm * 32 + mi * 16 + l16) * LDA + kk * 32 + quad * 8];
        #pragma unroll
        for (int ni = 0; ni < 2; ++ni)
            b[ni] = *(const short8*)&kfT[(wn * 32 + ni * 16 + l16) * LDA + kk * 32 + quad * 8];
        #pragma unroll
        for (int ni = 0; ni < 2; ++ni)
            #pragma unroll
            for (int mi = 0; mi < 2; ++mi)
                acc[mi][ni] = __builtin_amdgcn_mfma_f32_16x16x32_bf16(a[mi], b[ni], acc[mi][ni], 0, 0, 0);
    }

    // z[d] = sum_k kfT[d][k]
    {
        const int d = t & 63, seg = t >> 6;
        float s = 0.f;
        #pragma unroll
        for (int j2 = 0; j2 < 2; ++j2) {
            const short8 v8 = *(const short8*)&kfT[d * LDA + seg * 16 + j2 * 8];
            #pragma unroll
            for (int j = 0; j < 8; ++j) s += bf16_tof((unsigned short)v8[j]);
        }
        dpart[seg][d] = s;
    }
    __syncthreads();
    if (t < DH) {
        zsum[((size_t)(br * NHTOT + nh) * NCHUNK + c) * DH + t] =
            dpart[0][t] + dpart[1][t] + dpart[2][t] + dpart[3][t];
    }

    float* Sg = Ssum + ((size_t)(br * NHTOT + nh) * NCHUNK + c) * (DH * DH);
    #pragma unroll
    for (int mi = 0; mi < 2; ++mi)
        #pragma unroll
        for (int ni = 0; ni < 2; ++ni) {
            const int d = wn * 32 + ni * 16 + l16;
            #pragma unroll
            for (int r = 0; r < 4; ++r) {
                const int e = wm * 32 + mi * 16 + quad * 4 + r;
                Sg[e * DH + d] = acc[mi][ni][r];
            }
        }
}

// ---------------------------------------------------------------------------
// Kernel C (MFMA): per-(c,nh,br) partial num/den.  Inline exclusive prefix
// over raw chunk sums (avg 7.5 x 16 KB L2 reads) replaces the scan kernel.
// ---------------------------------------------------------------------------
__global__ __launch_bounds__(256) void attn_kernel(
    const unsigned short* __restrict__ qbuf, const unsigned short* __restrict__ kbuf,
    const unsigned short* __restrict__ vbuf,
    const float* __restrict__ Ssum, const float* __restrict__ zsum,
    const float* __restrict__ pw, const float* __restrict__ pb,
    float* __restrict__ numP, float* __restrict__ denP)
{
    const int c  = blockIdx.x;
    const int nh = blockIdx.y;
    const int br = blockIdx.z;
    const int n  = nh >> 3;
    const int h  = nh & (NHEAD - 1);
    const int t  = threadIdx.x;
    const int lane = t & 63, wave = t >> 6;
    const int quad = lane >> 4, l16 = lane & 15;
    const int wm = wave >> 1, wn = wave & 1;

    __shared__ unsigned short qfL[64 * LDA];  // [l][d]
    __shared__ unsigned short kfL[64 * LDA];  // [k][d]
    __shared__ unsigned short vTL[64 * LDA];  // [e][k]
    __shared__ unsigned short SpL[64 * LDA];  // [e][d]  (S^T prefix)
    __shared__ unsigned short scA[64 * LDA];  // masked scores [l][k]
    __shared__ float zl[DH];
    __shared__ float dpart[8][64];

    const size_t base = ((size_t)nh * LSEQ + (size_t)c * CHUNK) * DH;
    const float PI_ = 3.14159265358979323846f;

    // ---- inline exclusive prefix of S over chunks 0..c-1 ----
    int rr[4], cc4[4];
    #pragma unroll
    for (int i = 0; i < 4; ++i) {
        const int idx = i * 256 + t;
        rr[i]  = idx >> 4;
        cc4[i] = (idx & 15) * 4;
    }
    float sacc[16];
    #pragma unroll
    for (int j = 0; j < 16; ++j) sacc[j] = 0.f;
    {
        const float* Sg0 = Ssum + (size_t)(br * NHTOT + nh) * NCHUNK * (DH * DH);
        for (int cp = 0; cp < c; ++cp) {
            const float* Sgc = Sg0 + (size_t)cp * (DH * DH);
            #pragma unroll
            for (int i = 0; i < 4; ++i) {
                const float4 sv = *(const float4*)&Sgc[rr[i] * DH + cc4[i]];
                sacc[i * 4 + 0] += sv.x; sacc[i * 4 + 1] += sv.y;
                sacc[i * 4 + 2] += sv.z; sacc[i * 4 + 3] += sv.w;
            }
        }
    }
    if (t < DH) {
        float zacc = 0.f;
        const float* zg = zsum + (size_t)(br * NHTOT + nh) * NCHUNK * DH;
        for (int cp = 0; cp < c; ++cp) zacc += zg[cp * DH + t];
        zl[t] = zacc;
    }

    // ---- staging: q/k feature-mapped bf16, v transposed, Sp bf16 ----
    #pragma unroll
    for (int i = 0; i < 4; ++i) {
        const int r  = rr[i];
        const int c4 = cc4[i];
        const ushort4 qv = *(const ushort4*)&qbuf[base + (size_t)r * DH + c4];
        const ushort4 kv = *(const ushort4*)&kbuf[base + (size_t)r * DH + c4];
        const ushort4 vv = *(const ushort4*)&vbuf[base + (size_t)r * DH + c4];
        const unsigned short* pq0 = (const unsigned short*)&qv;
        const unsigned short* pk0 = (const unsigned short*)&kv;
        const unsigned short* pv0 = (const unsigned short*)&vv;
        ushort4 qh, kh, sh;
        unsigned short* pq = (unsigned short*)&qh;
        unsigned short* pk = (unsigned short*)&kh;
        unsigned short* ps = (unsigned short*)&sh;
        if (br == 0) {
            #pragma unroll
            for (int j = 0; j < 4; ++j) { pq[j] = pq0[j]; pk[j] = pk0[j]; }
        } else {
            const float4 wv  = *(const float4*)&pw[h * DH + c4];
            const float4 pbv = *(const float4*)&pb[h * DH + c4];
            const float w4[4] = {wv.x, wv.y, wv.z, wv.w};
            const float b4[4] = {pbv.x, pbv.y, pbv.z, pbv.w};
            const float pos = (float)(c * CHUNK + r);
            #pragma unroll
            for (int j = 0; j < 4; ++j) {
                const float bias = PI_ / (1.f + expf(-b4[j]));
                float tq, tk;
                if (br == 1) { tq = cosf(pos * w4[j] + bias); tk = cosf(pos * w4[j]); }
                else         { tq = sinf(pos * w4[j] + bias); tk = sinf(pos * w4[j]); }
                pq[j] = bf16_rne(bf16_tof(pq0[j]) * tq);
                pk[j] = bf16_rne(bf16_tof(pk0[j]) * tk);
            }
        }
        #pragma unroll
        for (int j = 0; j < 4; ++j) {
            ps[j] = bf16_rne(sacc[i * 4 + j]);
            vTL[(c4 + j) * LDA + r] = pv0[j];
        }
        *(ushort4*)&qfL[r * LDA + c4] = qh;
        *(ushort4*)&kfL[r * LDA + c4] = kh;
        *(ushort4*)&SpL[r * LDA + c4] = sh;
    }
    __syncthreads();

    // ---- GEMM1 (scores) + GEMM2 (num from S-prefix) ----
    floatx4 acc1[2][2], acc2[2][2];
    #pragma unroll
    for (int i = 0; i < 2; ++i)
        #pragma unroll
        for (int j = 0; j < 2; ++j) {
            acc1[i][j] = (floatx4){0.f, 0.f, 0.f, 0.f};
            acc2[i][j] = (floatx4){0.f, 0.f, 0.f, 0.f};
        }
    #pragma unroll
    for (int kk = 0; kk < 2; ++kk) {
        short8 a[2], b1[2], b2[2];
        #pragma unroll
        for (int mi = 0; mi < 2; ++mi)
            a[mi] = *(const short8*)&qfL[(wm * 32 + mi * 16 + l16) * LDA + kk * 32 + quad * 8];
        #pragma unroll
        for (int ni = 0; ni < 2; ++ni) {
            b1[ni] = *(const short8*)&kfL[(wn * 32 + ni * 16 + l16) * LDA + kk * 32 + quad * 8];
            b2[ni] = *(const short8*)&SpL[(wn * 32 + ni * 16 + l16) * LDA + kk * 32 + quad * 8];
        }
        #pragma unroll
        for (int ni = 0; ni < 2; ++ni)
            #pragma unroll
            for (int mi = 0; mi < 2; ++mi) {
                acc1[mi][ni] = __builtin_amdgcn_mfma_f32_16x16x32_bf16(a[mi], b1[ni], acc1[mi][ni], 0, 0, 0);
                acc2[mi][ni] = __builtin_amdgcn_mfma_f32_16x16x32_bf16(a[mi], b2[ni], acc2[mi][ni], 0, 0, 0);
            }
    }

    // den part 1: qf . z
    {
        const int l = t & 63, seg = t >> 6;
        float s = 0.f;
        #pragma unroll
        for (int j2 = 0; j2 < 2; ++j2) {
            const short8 v8 = *(const short8*)&qfL[l * LDA + seg * 16 + j2 * 8];
            #pragma unroll
            for (int j = 0; j < 8; ++j)
                s += bf16_tof((unsigned short)v8[j]) * zl[seg * 16 + j2 * 8 + j];
        }
        dpart[seg][l] = s;
    }

    // masked scores -> [l][k] bf16
    #pragma unroll
    for (int mi = 0; mi < 2; ++mi)
        #pragma unroll
        for (int ni = 0; ni < 2; ++ni) {
            const int kcol = wn * 32 + ni * 16 + l16;
            #pragma unroll
            for (int r = 0; r < 4; ++r) {
                const int lrow = wm * 32 + mi * 16 + quad * 4 + r;
                const float v = (kcol <= lrow) ? acc1[mi][ni][r] : 0.f;
                scA[lrow * LDA + kcol] = bf16_rne(v);
            }
        }
    __syncthreads();

    // ---- GEMM3: num += scores * v ----
    #pragma unroll
    for (int kk = 0; kk < 2; ++kk) {
        short8 a[2], b[2];
        #pragma unroll
        for (int mi = 0; mi < 2; ++mi)
            a[mi] = *(const short8*)&scA[(wm * 32 + mi * 16 + l16) * LDA + kk * 32 + quad * 8];
        #pragma unroll
        for (int ni = 0; ni < 2; ++ni)
            b[ni] = *(const short8*)&vTL[(wn * 32 + ni * 16 + l16) * LDA + kk * 32 + quad * 8];
        #pragma unroll
        for (int ni = 0; ni < 2; ++ni)
            #pragma unroll
            for (int mi = 0; mi < 2; ++mi)
                acc2[mi][ni] = __builtin_amdgcn_mfma_f32_16x16x32_bf16(a[mi], b[ni], acc2[mi][ni], 0, 0, 0);
    }

    // den part 2: row sums of masked scores
    {
        const int l = t & 63, seg = t >> 6;
        float s = 0.f;
        #pragma unroll
        for (int j2 = 0; j2 < 2; ++j2) {
            const short8 v8 = *(const short8*)&scA[l * LDA + seg * 16 + j2 * 8];
            #pragma unroll
            for (int j = 0; j < 8; ++j) s += bf16_tof((unsigned short)v8[j]);
        }
        dpart[4 + seg][l] = s;
    }
    __syncthreads();

    if (t < DH) {
        const float dl = dpart[0][t] + dpart[1][t] + dpart[2][t] + dpart[3][t]
                       + dpart[4][t] + dpart[5][t] + dpart[6][t] + dpart[7][t];
        denP[((size_t)(br * NHTOT + nh)) * LSEQ + c * CHUNK + t] = dl;
    }

    #pragma unroll
    for (int mi = 0; mi < 2; ++mi)
        #pragma unroll
        for (int ni = 0; ni < 2; ++ni) {
            const int e = wn * 32 + ni * 16 + l16;
            #pragma unroll
            for (int r = 0; r < 4; ++r) {
                const int l = c * CHUNK + wm * 32 + mi * 16 + quad * 4 + r;
                numP[(((size_t)br * 2 + n) * LSEQ + l) * DIM + h * DH + e] = acc2[mi][ni][r];
            }
        }
}

// ---------------------------------------------------------------------------
// Kernel D: out = (num0+num1+num2) / (den0+den1+den2).
// ---------------------------------------------------------------------------
__global__ __launch_bounds__(256) void combine_kernel(
    const float* __restrict__ numP, const float* __restrict__ denP,
    float* __restrict__ outp)
{
    const int i = blockIdx.x * 256 + threadIdx.x;
    const int row = i >> 7;
    const int ci  = i & 127;
    const int n = row >> 10, l = row & (LSEQ - 1), h = ci >> 4;
    const int nh = n * NHEAD + h;
    const float4* N = (const float4*)numP;
    const float4 a = N[i];
    const float4 b = N[i + 262144];
    const float4 cc = N[i + 524288];
    const float ds = denP[(size_t)nh * LSEQ + l]
                   + denP[((size_t)NHTOT + nh) * LSEQ + l]
                   + denP[((size_t)2 * NHTOT + nh) * LSEQ + l];
    const float inv = 1.f / ds;
    float4 o;
    o.x = (a.x + b.x + cc.x) * inv;
    o.y = (a.y + b.y + cc.y) * inv;
    o.z = (a.z + b.z + cc.z) * inv;
    o.w = (a.w + b.w + cc.w) * inv;
    ((float4*)outp)[i] = o;
}

extern "C" void kernel_launch(void* const* d_in, const int* in_sizes, int n_in,
                              void* d_out, int out_size, void* d_ws, size_t ws_size,
                              hipStream_t stream) {
    const float* query = (const float*)d_in[0];
    const float* key   = (const float*)d_in[1];
    const float* Wq    = (const float*)d_in[2];
    const float* Wk    = (const float*)d_in[3];
    const float* Wv    = (const float*)d_in[4];
    const float* pw    = (const float*)d_in[5];
    const float* pb    = (const float*)d_in[6];

    unsigned short* U = (unsigned short*)d_ws;
    float* F = (float*)d_ws;
    unsigned short* qbuf = U;                 // 1,048,576 u16 = 2 MB
    unsigned short* kbuf = U + 1048576;
    unsigned short* vbuf = U + 2097152;       // ends at 6 MB
    float* Ssum = F + 1572864;                // 3,145,728 floats ([br][nh][c][e][d])
    float* zsum = F + 4718592;                // 49,152
    float* numP = F + 4767744;                // 3,145,728
    float* denP = F + 7913472;                // 49,152 -> 31.9 MB total

    proj_kernel<<<dim3(32, 8, 3), 256, 0, stream>>>(
        query, key, Wq, Wk, Wv, qbuf, kbuf, vbuf);
    chunksum_kernel<<<dim3(NCHUNK, NHTOT, 3), 256, 0, stream>>>(
        kbuf, vbuf, pw, Ssum, zsum);
    attn_kernel<<<dim3(NCHUNK, NHTOT, 3), 256, 0, stream>>>(
        qbuf, kbuf, vbuf, Ssum, zsum, pw, pb, numP, denP);
    combine_kernel<<<dim3(1024), 256, 0, stream>>>(numP, denP, (float*)d_out);
}

// Round 9
// 122.304 us; speedup vs baseline: 1.0789x; 1.0789x over previous
//
#include <hip/hip_runtime.h>
#include <hip/hip_bf16.h>

#define LSEQ   1024
#define NHEAD  8
#define DH     64
#define DIM    512
#define CHUNK  64
#define NCHUNK 16
#define NHTOT  16
#define LDB    68    // ushort LDS row stride for proj
#define LDA    72    // ushort LDS row stride for attn/chunksum (144 B, 16B-aligned)

typedef __attribute__((ext_vector_type(8))) short short8;
typedef __attribute__((ext_vector_type(4))) float floatx4;

__device__ __forceinline__ float softplusf_(float x) {
    if (x > 20.f) return x;
    return log1pf(expf(x));
}
__device__ __forceinline__ unsigned short bf16_rne(float x) {
    unsigned int u = __float_as_uint(x);
    u += 0x7FFFu + ((u >> 16) & 1u);
    return (unsigned short)(u >> 16);
}
__device__ __forceinline__ float bf16_tof(unsigned short h) {
    return __uint_as_float(((unsigned int)h) << 16);
}

// ---------------------------------------------------------------------------
// Kernel A: C = X @ W^T, single-pass bf16 MFMA.  64x64 tile, grid (32,8,3).
// Output: bf16 [n*H+h][l][d].
// ---------------------------------------------------------------------------
__global__ __launch_bounds__(256) void proj_kernel(
    const float* __restrict__ query, const float* __restrict__ key,
    const float* __restrict__ Wq, const float* __restrict__ Wk,
    const float* __restrict__ Wv,
    unsigned short* __restrict__ qbuf, unsigned short* __restrict__ kbuf,
    unsigned short* __restrict__ vbuf)
{
    const int mt  = blockIdx.x;
    const int ot  = blockIdx.y;
    const int sel = blockIdx.z;
    const int t   = threadIdx.x;

    const float* __restrict__ X = (sel == 0) ? query : key;
    const float* __restrict__ W = (sel == 0) ? Wq : (sel == 1) ? Wk : Wv;
    unsigned short* __restrict__ obuf = (sel == 0) ? qbuf : (sel == 1) ? kbuf : vbuf;

    __shared__ unsigned short As[64 * LDB];
    __shared__ unsigned short Bs[64 * LDB];

    const int m0 = mt * 64, o0 = ot * 64;
    const int lane = t & 63, wave = t >> 6;
    const int quad = lane >> 4, l16 = lane & 15;
    const int wm = wave >> 1, wn = wave & 1;

    const int srow = t >> 2;
    const int sc16 = (t & 3) * 16;

    floatx4 acc[2][2];
    #pragma unroll
    for (int i = 0; i < 2; ++i)
        #pragma unroll
        for (int j = 0; j < 2; ++j) acc[i][j] = (floatx4){0.f, 0.f, 0.f, 0.f};

    float4 ax[4], bx4[4];
    #pragma unroll
    for (int i = 0; i < 4; ++i) {
        ax[i]  = *(const float4*)&X[(size_t)(m0 + srow) * DIM + sc16 + i * 4];
        bx4[i] = *(const float4*)&W[(size_t)(o0 + srow) * DIM + sc16 + i * 4];
    }

    for (int kt = 0; kt < DIM; kt += 64) {
        __syncthreads();
        {
            short8 a0, a1, b0, b1;
            #pragma unroll
            for (int i = 0; i < 2; ++i) {
                const float va[4] = {ax[i].x, ax[i].y, ax[i].z, ax[i].w};
                const float vb[4] = {bx4[i].x, bx4[i].y, bx4[i].z, bx4[i].w};
                #pragma unroll
                for (int j = 0; j < 4; ++j) {
                    a0[i * 4 + j] = (short)bf16_rne(va[j]);
                    b0[i * 4 + j] = (short)bf16_rne(vb[j]);
                }
            }
            #pragma unroll
            for (int i = 2; i < 4; ++i) {
                const float va[4] = {ax[i].x, ax[i].y, ax[i].z, ax[i].w};
                const float vb[4] = {bx4[i].x, bx4[i].y, bx4[i].z, bx4[i].w};
                #pragma unroll
                for (int j = 0; j < 4; ++j) {
                    a1[(i - 2) * 4 + j] = (short)bf16_rne(va[j]);
                    b1[(i - 2) * 4 + j] = (short)bf16_rne(vb[j]);
                }
            }
            *(short8*)&As[srow * LDB + sc16]     = a0;
            *(short8*)&As[srow * LDB + sc16 + 8] = a1;
            *(short8*)&Bs[srow * LDB + sc16]     = b0;
            *(short8*)&Bs[srow * LDB + sc16 + 8] = b1;
        }
        __syncthreads();

        if (kt + 64 < DIM) {
            #pragma unroll
            for (int i = 0; i < 4; ++i) {
                ax[i]  = *(const float4*)&X[(size_t)(m0 + srow) * DIM + kt + 64 + sc16 + i * 4];
                bx4[i] = *(const float4*)&W[(size_t)(o0 + srow) * DIM + kt + 64 + sc16 + i * 4];
            }
        }

        #pragma unroll
        for (int s = 0; s < 2; ++s) {
            short8 af[2], bf[2];
            #pragma unroll
            for (int mi = 0; mi < 2; ++mi)
                af[mi] = *(const short8*)&As[(wm * 32 + mi * 16 + l16) * LDB + s * 32 + quad * 8];
            #pragma unroll
            for (int ni = 0; ni < 2; ++ni)
                bf[ni] = *(const short8*)&Bs[(wn * 32 + ni * 16 + l16) * LDB + s * 32 + quad * 8];
            #pragma unroll
            for (int ni = 0; ni < 2; ++ni)
                #pragma unroll
                for (int mi = 0; mi < 2; ++mi)
                    acc[mi][ni] = __builtin_amdgcn_mfma_f32_16x16x32_bf16(af[mi], bf[ni], acc[mi][ni], 0, 0, 0);
        }
    }

    const int h = ot;
    #pragma unroll
    for (int mi = 0; mi < 2; ++mi)
        #pragma unroll
        for (int ni = 0; ni < 2; ++ni) {
            const int d = wn * 32 + ni * 16 + l16;
            #pragma unroll
            for (int r = 0; r < 4; ++r) {
                const int m = m0 + wm * 32 + mi * 16 + quad * 4 + r;
                const int n = m >> 10, l = m & (LSEQ - 1);
                float val = acc[mi][ni][r];
                if (sel < 2) val = softplusf_(val);
                obuf[(((size_t)(n * NHEAD + h)) * LSEQ + l) * DH + d] = bf16_rne(val);
            }
        }
}

// ---------------------------------------------------------------------------
// Kernel B (MFMA): per-(c,nh,br) chunk sums, stored TRANSPOSED f32:
//   Ssum[br][nh][c][e][d] = sum_k v[k][e]*kf[k][d];  zsum[...][d] = sum_k kf[k][d]
// ---------------------------------------------------------------------------
__global__ __launch_bounds__(256) void chunksum_kernel(
    const unsigned short* __restrict__ kbuf, const unsigned short* __restrict__ vbuf,
    const float* __restrict__ pw,
    float* __restrict__ Ssum, float* __restrict__ zsum)
{
    const int c  = blockIdx.x;
    const int nh = blockIdx.y;
    const int br = blockIdx.z;
    const int h  = nh & (NHEAD - 1);
    const int t  = threadIdx.x;
    const int lane = t & 63, wave = t >> 6;
    const int quad = lane >> 4, l16 = lane & 15;
    const int wm = wave >> 1, wn = wave & 1;

    __shared__ unsigned short kfT[64 * LDA];  // [d][k]
    __shared__ unsigned short vT[64 * LDA];   // [e][k]
    __shared__ float dpart[4][64];

    const size_t base = ((size_t)nh * LSEQ + (size_t)c * CHUNK) * DH;

    #pragma unroll
    for (int i = 0; i < 4; ++i) {
        const int idx = i * 256 + t;
        const int r  = idx >> 4;          // k
        const int c4 = (idx & 15) * 4;    // d / e base
        const ushort4 kv = *(const ushort4*)&kbuf[base + (size_t)r * DH + c4];
        const ushort4 vv = *(const ushort4*)&vbuf[base + (size_t)r * DH + c4];
        const unsigned short* pk = (const unsigned short*)&kv;
        const unsigned short* pv = (const unsigned short*)&vv;
        float tk[4] = {1.f, 1.f, 1.f, 1.f};
        if (br != 0) {
            const float4 wv = *(const float4*)&pw[h * DH + c4];
            const float w4[4] = {wv.x, wv.y, wv.z, wv.w};
            const float pos = (float)(c * CHUNK + r);
            #pragma unroll
            for (int j = 0; j < 4; ++j)
                tk[j] = (br == 1) ? cosf(pos * w4[j]) : sinf(pos * w4[j]);
        }
        #pragma unroll
        for (int j = 0; j < 4; ++j) {
            kfT[(c4 + j) * LDA + r] = (br == 0) ? pk[j]
                                     : bf16_rne(bf16_tof(pk[j]) * tk[j]);
            vT[(c4 + j) * LDA + r] = pv[j];
        }
    }
    __syncthreads();

    floatx4 acc[2][2];
    #pragma unroll
    for (int i = 0; i < 2; ++i)
        #pragma unroll
        for (int j = 0; j < 2; ++j) acc[i][j] = (floatx4){0.f, 0.f, 0.f, 0.f};

    #pragma unroll
    for (int kk = 0; kk < 2; ++kk) {
        short8 a[2], b[2];
        #pragma unroll
        for (int mi = 0; mi < 2; ++mi)
            a[mi] = *(const short8*)&vT[(wm * 32 + mi * 16 + l16) * LDA + kk * 32 + quad * 8];
        #pragma unroll
        for (int ni = 0; ni < 2; ++ni)
            b[ni] = *(const short8*)&kfT[(wn * 32 + ni * 16 + l16) * LDA + kk * 32 + quad * 8];
        #pragma unroll
        for (int ni = 0; ni < 2; ++ni)
            #pragma unroll
            for (int mi = 0; mi < 2; ++mi)
                acc[mi][ni] = __builtin_amdgcn_mfma_f32_16x16x32_bf16(a[mi], b[ni], acc[mi][ni], 0, 0, 0);
    }

    // z[d] = sum_k kfT[d][k]
    {
        const int d = t & 63, seg = t >> 6;
        float s = 0.f;
        #pragma unroll
        for (int j2 = 0; j2 < 2; ++j2) {
            const short8 v8 = *(const short8*)&kfT[d * LDA + seg * 16 + j2 * 8];
            #pragma unroll
            for (int j = 0; j < 8; ++j) s += bf16_tof((unsigned short)v8[j]);
        }
        dpart[seg][d] = s;
    }
    __syncthreads();
    if (t < DH) {
        zsum[((size_t)(br * NHTOT + nh) * NCHUNK + c) * DH + t] =
            dpart[0][t] + dpart[1][t] + dpart[2][t] + dpart[3][t];
    }

    float* Sg = Ssum + ((size_t)(br * NHTOT + nh) * NCHUNK + c) * (DH * DH);
    #pragma unroll
    for (int mi = 0; mi < 2; ++mi)
        #pragma unroll
        for (int ni = 0; ni < 2; ++ni) {
            const int d = wn * 32 + ni * 16 + l16;
            #pragma unroll
            for (int r = 0; r < 4; ++r) {
                const int e = wm * 32 + mi * 16 + quad * 4 + r;
                Sg[e * DH + d] = acc[mi][ni][r];
            }
        }
}

// ---------------------------------------------------------------------------
// Kernel B2: in-place exclusive prefix over chunks; grid (48, 16) = 768 blocks.
// (Measured R8: inlining this into attn as a serial per-block loop cost +8 us
//  from load imbalance — keep it as a dedicated parallel kernel.)
// ---------------------------------------------------------------------------
__global__ __launch_bounds__(256) void scan_kernel(
    float* __restrict__ Ssum, float* __restrict__ zsum)
{
    const int b = blockIdx.x;
    const int s = blockIdx.y;
    const int idx = s * 256 + threadIdx.x;

    float* S = Ssum + (size_t)b * NCHUNK * (DH * DH);
    float v[NCHUNK];
    #pragma unroll
    for (int c = 0; c < NCHUNK; ++c) v[c] = S[c * (DH * DH) + idx];
    float run = 0.f;
    #pragma unroll
    for (int c = 0; c < NCHUNK; ++c) {
        const float nv = v[c];
        S[c * (DH * DH) + idx] = run;
        run += nv;
    }
    if (s == 0 && threadIdx.x < DH) {
        float* z = zsum + (size_t)b * NCHUNK * DH;
        float zv[NCHUNK];
        #pragma unroll
        for (int c = 0; c < NCHUNK; ++c) zv[c] = z[c * DH + threadIdx.x];
        float zr = 0.f;
        #pragma unroll
        for (int c = 0; c < NCHUNK; ++c) {
            const float nv = zv[c];
            z[c * DH + threadIdx.x] = zr;
            zr += nv;
        }
    }
}

// ---------------------------------------------------------------------------
// Kernel C (MFMA): per-(c,nh,br) partial num/den; Ssum/zsum hold prefixes.
// ---------------------------------------------------------------------------
__global__ __launch_bounds__(256) void attn_kernel(
    const unsigned short* __restrict__ qbuf, const unsigned short* __restrict__ kbuf,
    const unsigned short* __restrict__ vbuf,
    const float* __restrict__ Ssum, const float* __restrict__ zsum,
    const float* __restrict__ pw, const float* __restrict__ pb,
    float* __restrict__ numP, float* __restrict__ denP)
{
    const int c  = blockIdx.x;
    const int nh = blockIdx.y;
    const int br = blockIdx.z;
    const int n  = nh >> 3;
    const int h  = nh & (NHEAD - 1);
    const int t  = threadIdx.x;
    const int lane = t & 63, wave = t >> 6;
    const int quad = lane >> 4, l16 = lane & 15;
    const int wm = wave >> 1, wn = wave & 1;

    __shared__ unsigned short qfL[64 * LDA];  // [l][d]
    __shared__ unsigned short kfL[64 * LDA];  // [k][d]
    __shared__ unsigned short vTL[64 * LDA];  // [e][k]
    __shared__ unsigned short SpL[64 * LDA];  // [e][d]  (S^T prefix)
    __shared__ unsigned short scA[64 * LDA];  // masked scores [l][k]
    __shared__ float zl[DH];
    __shared__ float dpart[8][64];

    const size_t base = ((size_t)nh * LSEQ + (size_t)c * CHUNK) * DH;
    const float* Sg = Ssum + ((size_t)(br * NHTOT + nh) * NCHUNK + c) * (DH * DH);
    const float PI_ = 3.14159265358979323846f;

    #pragma unroll
    for (int i = 0; i < 4; ++i) {
        const int idx = i * 256 + t;
        const int r  = idx >> 4;
        const int c4 = (idx & 15) * 4;
        const ushort4 qv = *(const ushort4*)&qbuf[base + (size_t)r * DH + c4];
        const ushort4 kv = *(const ushort4*)&kbuf[base + (size_t)r * DH + c4];
        const ushort4 vv = *(const ushort4*)&vbuf[base + (size_t)r * DH + c4];
        const float4  sv = *(const float4*)&Sg[r * DH + c4];
        const unsigned short* pq0 = (const unsigned short*)&qv;
        const unsigned short* pk0 = (const unsigned short*)&kv;
        const unsigned short* pv0 = (const unsigned short*)&vv;
        ushort4 qh, kh, sh;
        unsigned short* pq = (unsigned short*)&qh;
        unsigned short* pk = (unsigned short*)&kh;
        unsigned short* ps = (unsigned short*)&sh;
        if (br == 0) {
            #pragma unroll
            for (int j = 0; j < 4; ++j) { pq[j] = pq0[j]; pk[j] = pk0[j]; }
        } else {
            const float4 wv  = *(const float4*)&pw[h * DH + c4];
            const float4 pbv = *(const float4*)&pb[h * DH + c4];
            const float w4[4] = {wv.x, wv.y, wv.z, wv.w};
            const float b4[4] = {pbv.x, pbv.y, pbv.z, pbv.w};
            const float pos = (float)(c * CHUNK + r);
            #pragma unroll
            for (int j = 0; j < 4; ++j) {
                const float bias = PI_ / (1.f + expf(-b4[j]));
                float tq, tk;
                if (br == 1) { tq = cosf(pos * w4[j] + bias); tk = cosf(pos * w4[j]); }
                else         { tq = sinf(pos * w4[j] + bias); tk = sinf(pos * w4[j]); }
                pq[j] = bf16_rne(bf16_tof(pq0[j]) * tq);
                pk[j] = bf16_rne(bf16_tof(pk0[j]) * tk);
            }
        }
        const float s4[4] = {sv.x, sv.y, sv.z, sv.w};
        #pragma unroll
        for (int j = 0; j < 4; ++j) {
            ps[j] = bf16_rne(s4[j]);
            vTL[(c4 + j) * LDA + r] = pv0[j];
        }
        *(ushort4*)&qfL[r * LDA + c4] = qh;
        *(ushort4*)&kfL[r * LDA + c4] = kh;
        *(ushort4*)&SpL[r * LDA + c4] = sh;
    }
    if (t < DH)
        zl[t] = zsum[((size_t)(br * NHTOT + nh) * NCHUNK + c) * DH + t];
    __syncthreads();

    // ---- GEMM1 (scores) + GEMM2 (num from S-prefix) ----
    floatx4 acc1[2][2], acc2[2][2];
    #pragma unroll
    for (int i = 0; i < 2; ++i)
        #pragma unroll
        for (int j = 0; j < 2; ++j) {
            acc1[i][j] = (floatx4){0.f, 0.f, 0.f, 0.f};
            acc2[i][j] = (floatx4){0.f, 0.f, 0.f, 0.f};
        }
    #pragma unroll
    for (int kk = 0; kk < 2; ++kk) {
        short8 a[2], b1[2], b2[2];
        #pragma unroll
        for (int mi = 0; mi < 2; ++mi)
            a[mi] = *(const short8*)&qfL[(wm * 32 + mi * 16 + l16) * LDA + kk * 32 + quad * 8];
        #pragma unroll
        for (int ni = 0; ni < 2; ++ni) {
            b1[ni] = *(const short8*)&kfL[(wn * 32 + ni * 16 + l16) * LDA + kk * 32 + quad * 8];
            b2[ni] = *(const short8*)&SpL[(wn * 32 + ni * 16 + l16) * LDA + kk * 32 + quad * 8];
        }
        #pragma unroll
        for (int ni = 0; ni < 2; ++ni)
            #pragma unroll
            for (int mi = 0; mi < 2; ++mi) {
                acc1[mi][ni] = __builtin_amdgcn_mfma_f32_16x16x32_bf16(a[mi], b1[ni], acc1[mi][ni], 0, 0, 0);
                acc2[mi][ni] = __builtin_amdgcn_mfma_f32_16x16x32_bf16(a[mi], b2[ni], acc2[mi][ni], 0, 0, 0);
            }
    }

    // den part 1: qf . z
    {
        const int l = t & 63, seg = t >> 6;
        float s = 0.f;
        #pragma unroll
        for (int j2 = 0; j2 < 2; ++j2) {
            const short8 v8 = *(const short8*)&qfL[l * LDA + seg * 16 + j2 * 8];
            #pragma unroll
            for (int j = 0; j < 8; ++j)
                s += bf16_tof((unsigned short)v8[j]) * zl[seg * 16 + j2 * 8 + j];
        }
        dpart[seg][l] = s;
    }

    // masked scores -> [l][k] bf16
    #pragma unroll
    for (int mi = 0; mi < 2; ++mi)
        #pragma unroll
        for (int ni = 0; ni < 2; ++ni) {
            const int kcol = wn * 32 + ni * 16 + l16;
            #pragma unroll
            for (int r = 0; r < 4; ++r) {
                const int lrow = wm * 32 + mi * 16 + quad * 4 + r;
                const float v = (kcol <= lrow) ? acc1[mi][ni][r] : 0.f;
                scA[lrow * LDA + kcol] = bf16_rne(v);
            }
        }
    __syncthreads();

    // ---- GEMM3: num += scores * v ----
    #pragma unroll
    for (int kk = 0; kk < 2; ++kk) {
        short8 a[2], b[2];
        #pragma unroll
        for (int mi = 0; mi < 2; ++mi)
            a[mi] = *(const short8*)&scA[(wm * 32 + mi * 16 + l16) * LDA + kk * 32 + quad * 8];
        #pragma unroll
        for (int ni = 0; ni < 2; ++ni)
            b[ni] = *(const short8*)&vTL[(wn * 32 + ni * 16 + l16) * LDA + kk * 32 + quad * 8];
        #pragma unroll
        for (int ni = 0; ni < 2; ++ni)
            #pragma unroll
            for (int mi = 0; mi < 2; ++mi)
                acc2[mi][ni] = __builtin_amdgcn_mfma_f32_16x16x32_bf16(a[mi], b[ni], acc2[mi][ni], 0, 0, 0);
    }

    // den part 2: row sums of masked scores
    {
        const int l = t & 63, seg = t >> 6;
        float s = 0.f;
        #pragma unroll
        for (int j2 = 0; j2 < 2; ++j2) {
            const short8 v8 = *(const short8*)&scA[l * LDA + seg * 16 + j2 * 8];
            #pragma unroll
            for (int j = 0; j < 8; ++j) s += bf16_tof((unsigned short)v8[j]);
        }
        dpart[4 + seg][l] = s;
    }
    __syncthreads();

    if (t < DH) {
        const float dl = dpart[0][t] + dpart[1][t] + dpart[2][t] + dpart[3][t]
                       + dpart[4][t] + dpart[5][t] + dpart[6][t] + dpart[7][t];
        denP[((size_t)(br * NHTOT + nh)) * LSEQ + c * CHUNK + t] = dl;
    }

    #pragma unroll
    for (int mi = 0; mi < 2; ++mi)
        #pragma unroll
        for (int ni = 0; ni < 2; ++ni) {
            const int e = wn * 32 + ni * 16 + l16;
            #pragma unroll
            for (int r = 0; r < 4; ++r) {
                const int l = c * CHUNK + wm * 32 + mi * 16 + quad * 4 + r;
                numP[(((size_t)br * 2 + n) * LSEQ + l) * DIM + h * DH + e] = acc2[mi][ni][r];
            }
        }
}

// ---------------------------------------------------------------------------
// Kernel D: out = (num0+num1+num2) / (den0+den1+den2).
// ---------------------------------------------------------------------------
__global__ __launch_bounds__(256) void combine_kernel(
    const float* __restrict__ numP, const float* __restrict__ denP,
    float* __restrict__ outp)
{
    const int i = blockIdx.x * 256 + threadIdx.x;
    const int row = i >> 7;
    const int ci  = i & 127;
    const int n = row >> 10, l = row & (LSEQ - 1), h = ci >> 4;
    const int nh = n * NHEAD + h;
    const float4* N = (const float4*)numP;
    const float4 a = N[i];
    const float4 b = N[i + 262144];
    const float4 cc = N[i + 524288];
    const float ds = denP[(size_t)nh * LSEQ + l]
                   + denP[((size_t)NHTOT + nh) * LSEQ + l]
                   + denP[((size_t)2 * NHTOT + nh) * LSEQ + l];
    const float inv = 1.f / ds;
    float4 o;
    o.x = (a.x + b.x + cc.x) * inv;
    o.y = (a.y + b.y + cc.y) * inv;
    o.z = (a.z + b.z + cc.z) * inv;
    o.w = (a.w + b.w + cc.w) * inv;
    ((float4*)outp)[i] = o;
}

extern "C" void kernel_launch(void* const* d_in, const int* in_sizes, int n_in,
                              void* d_out, int out_size, void* d_ws, size_t ws_size,
                              hipStream_t stream) {
    const float* query = (const float*)d_in[0];
    const float* key   = (const float*)d_in[1];
    const float* Wq    = (const float*)d_in[2];
    const float* Wk    = (const float*)d_in[3];
    const float* Wv    = (const float*)d_in[4];
    const float* pw    = (const float*)d_in[5];
    const float* pb    = (const float*)d_in[6];

    unsigned short* U = (unsigned short*)d_ws;
    float* F = (float*)d_ws;
    unsigned short* qbuf = U;                 // 1,048,576 u16 = 2 MB
    unsigned short* kbuf = U + 1048576;
    unsigned short* vbuf = U + 2097152;       // ends at 6 MB
    float* Ssum = F + 1572864;                // 3,145,728 floats ([br][nh][c][e][d])
    float* zsum = F + 4718592;                // 49,152
    float* numP = F + 4767744;                // 3,145,728
    float* denP = F + 7913472;                // 49,152 -> 31.9 MB total

    proj_kernel<<<dim3(32, 8, 3), 256, 0, stream>>>(
        query, key, Wq, Wk, Wv, qbuf, kbuf, vbuf);
    chunksum_kernel<<<dim3(NCHUNK, NHTOT, 3), 256, 0, stream>>>(
        kbuf, vbuf, pw, Ssum, zsum);
    scan_kernel<<<dim3(3 * NHTOT, NCHUNK), 256, 0, stream>>>(Ssum, zsum);
    attn_kernel<<<dim3(NCHUNK, NHTOT, 3), 256, 0, stream>>>(
        qbuf, kbuf, vbuf, Ssum, zsum, pw, pb, numP, denP);
    combine_kernel<<<dim3(1024), 256, 0, stream>>>(numP, denP, (float*)d_out);
}